// Round 6
// baseline (1909.852 us; speedup 1.0000x reference)
//
#include <hip/hip_runtime.h>

// Fused 4x upsample, 256-thread r0 geometry with r3-verified 0-based indexing (dispatch 1),
// plus 3 store-free phase-ablation kernels (dispatches 2-4) looped to land in rocprof top-5.
// MEASUREMENT ROUND: dur_us will be inflated by ~400-600us of ablation dispatches.

#define SINS 52      // sIn row stride (48 used + 4 pad; float4-aligned)
#define SMS 132      // sMid row stride (128 + 4 pad)

__device__ inline void fma4(float4& a, float t, const float4& r) {
    a.x += t * r.x; a.y += t * r.y; a.z += t * r.z; a.w += t * r.w;
}

__device__ __forceinline__ void compute_G(const float* __restrict__ kern, float* sG, int tid) {
    if (tid < 80) {
        const int s = tid - 34;
        int jlo = (s - 10) >> 1;
        int jhi = (s + 11) >> 1;
        if (jlo < -11) jlo = -11;
        if (jhi > 11) jhi = 11;
        float acc = 0.f;
        for (int j = jlo; j <= jhi; ++j)
            acc += kern[11 + s - 2 * j] * kern[11 + j];
        sG[tid] = acc;
    }
}

// 0-based patch: sIn[pi][pj] = inC[(N0y+1+pi+rowoff)&255][(N0x+1+pj)&255]
__device__ __forceinline__ void load_patch(const float* __restrict__ inC,
                                           float (*sIn)[SINS], int tid,
                                           int N0y, int N0x, int rowoff) {
    const int gj0 = (N0x + 1) & 255;            // ≡ 0 mod 8 -> float4-aligned
    if (gj0 <= 208) {
#pragma unroll
        for (int it = 0; it < 3; ++it) {
            const int idx = tid + it * 256;     // 0..575
            if (idx < 576) {
                const int pi = idx / 12, m = idx % 12;
                const int gi = (N0y + 1 + pi + rowoff + 256) & 255;
                *(float4*)&sIn[pi][4 * m] =
                    *(const float4*)&inC[gi * 256 + gj0 + 4 * m];
            }
        }
    } else {
#pragma unroll
        for (int it = 0; it < 9; ++it) {
            const int idx = tid + it * 256;     // 0..2303
            const int pi = idx / 48, pj = idx % 48;
            const int gi = (N0y + 1 + pi + rowoff + 256) & 255;
            const int gj = (N0x + 1 + pj + 256) & 255;
            sIn[pi][pj] = inC[gi * 256 + gj];
        }
    }
}

__device__ __forceinline__ void read_taps(const float* sG, float* tapA, float* tC6) {
#pragma unroll
    for (int k = 0; k < 17; ++k) tapA[k] = sG[1 + 4 * k];
#pragma unroll
    for (int m = 0; m < 6; ++m) tC6[m] = sG[12 + 4 * m];
}

// horizontal: quad c reads sIn[row][c..c+16] (0-based), writes sMid[row][4c..4c+3]
__device__ __forceinline__ void horiz_pass(const float (*sIn)[SINS], float (*sMid)[SMS],
                                           const float* tapA, const float* tC6,
                                           int tid, int rowxor) {
#pragma unroll
    for (int it = 0; it < 6; ++it) {
        const int idx = tid + it * 256;         // 0..1535
        const int c = idx & 31, row = (idx >> 5) ^ rowxor;
        float a0 = 0.f, a1 = 0.f, a2 = 0.f, a3 = 0.f;
#pragma unroll
        for (int k = 0; k < 17; ++k) {
            const float w = sIn[row][c + 16 - k];
            a1 += tapA[k] * w;
            a3 += tapA[16 - k] * w;
            if (k >= 3 && k <= 14) {
                const int m2 = k - 3;
                a0 += tC6[m2 < 6 ? m2 : 11 - m2] * w;
            }
            if (k == 8) a2 = w;
        }
        float4 v; v.x = a0; v.y = a1; v.z = a2; v.w = a3;
        *(float4*)&sMid[row][4 * c] = v;
    }
}

// vertical: rowgroup R=4*gp+i reads mid rows R..R+16 (d=1..20, row=4gp+d-1, k=i+17-d)
__device__ __forceinline__ void vert_pass(const float (*sMid)[SMS],
                                          const float* tapA, const float* tC6,
                                          int c, int gp, float4 A[4][4]) {
#pragma unroll
    for (int d = 1; d <= 20; ++d) {
        const float4 R = *(const float4*)&sMid[4 * gp + d - 1][4 * c];
#pragma unroll
        for (int i = 0; i < 4; ++i) {
            const int k = i + 17 - d;
            if (k < 0 || k > 16) continue;
            fma4(A[i][1], tapA[k], R);
            fma4(A[i][3], tapA[16 - k], R);
            if (k >= 3 && k <= 14) {
                const int m = k - 3;
                fma4(A[i][0], tC6[m < 6 ? m : 11 - m], R);
            }
            if (k == 8) A[i][2] = R;
        }
    }
}

// ---------------- dispatch 1: the real kernel ----------------
__global__ __launch_bounds__(256, 4) void up4_fused(
    const float* __restrict__ in, const float* __restrict__ kern,
    float* __restrict__ out) {
    __shared__ float sG[80];
    __shared__ __attribute__((aligned(16))) float sMid[48][SMS];
    __shared__ __attribute__((aligned(16))) float sIn[48][SINS];

    const int tid = threadIdx.x;
    const int tX = blockIdx.x, tY = blockIdx.y, ch = blockIdx.z;

    compute_G(kern, sG, tid);
    const float* inC = in + (size_t)ch * 256 * 256;
    const int N0y = 32 * tY - 9, N0x = 32 * tX - 9;
    load_patch(inC, sIn, tid, N0y, N0x, 0);
    __syncthreads();

    float tapA[17], tC6[6];
    read_taps(sG, tapA, tC6);

    horiz_pass(sIn, sMid, tapA, tC6, tid, 0);
    __syncthreads();

    const int c = tid & 31, gp = tid >> 5;
    float4 A[4][4];
#pragma unroll
    for (int i = 0; i < 4; ++i)
#pragma unroll
        for (int p = 0; p < 4; ++p) { A[i][p].x = 0.f; A[i][p].y = 0.f; A[i][p].z = 0.f; A[i][p].w = 0.f; }
    vert_pass(sMid, tapA, tC6, c, gp, A);

    float* outC = out + (size_t)ch * 1024 * 1024;
    const int row0 = 128 * tY + 16 * gp, col = 128 * tX + 4 * c;
#pragma unroll
    for (int i = 0; i < 4; ++i)
#pragma unroll
        for (int p = 0; p < 4; ++p)
            *(float4*)&outC[(size_t)(row0 + 4 * i + p) * 1024 + col] = A[i][p];
}

// ---------------- dispatch 2: load phase x32 ----------------
__global__ __launch_bounds__(256, 4) void abl_load(const float* __restrict__ in) {
    __shared__ __attribute__((aligned(16))) float sIn[48][SINS];
    const int tid = threadIdx.x;
    const int tX = blockIdx.x, tY = blockIdx.y, ch = blockIdx.z;
    const float* inC = in + (size_t)ch * 256 * 256;
    const int N0y = 32 * tY - 9, N0x = 32 * tX - 9;
#pragma unroll 1
    for (int l = 0; l < 32; ++l) {
        load_patch(inC, sIn, tid, N0y, N0x, l);
        __syncthreads();
    }
    float v = sIn[(tid * 13) % 48][(tid * 29) % 48];
    asm volatile("" :: "v"(v));
}

// ---------------- dispatch 3: load once + horizontal x16 ----------------
__global__ __launch_bounds__(256, 4) void abl_horiz(
    const float* __restrict__ in, const float* __restrict__ kern) {
    __shared__ float sG[80];
    __shared__ __attribute__((aligned(16))) float sMid[48][SMS];
    __shared__ __attribute__((aligned(16))) float sIn[48][SINS];
    const int tid = threadIdx.x;
    const int tX = blockIdx.x, tY = blockIdx.y, ch = blockIdx.z;
    compute_G(kern, sG, tid);
    const float* inC = in + (size_t)ch * 256 * 256;
    const int N0y = 32 * tY - 9, N0x = 32 * tX - 9;
    load_patch(inC, sIn, tid, N0y, N0x, 0);
    __syncthreads();
    float tapA[17], tC6[6];
    read_taps(sG, tapA, tC6);
#pragma unroll 1
    for (int l = 0; l < 16; ++l) {
        horiz_pass(sIn, sMid, tapA, tC6, tid, l & 7);
        __syncthreads();
    }
    float v = sMid[(tid * 13) % 48][(tid * 29) & 127];
    asm volatile("" :: "v"(v));
}

// ---------------- dispatch 4: load+H once + vertical x16 ----------------
__global__ __launch_bounds__(256, 4) void abl_vert(
    const float* __restrict__ in, const float* __restrict__ kern) {
    __shared__ float sG[80];
    __shared__ __attribute__((aligned(16))) float sMid[48][SMS];
    __shared__ __attribute__((aligned(16))) float sIn[48][SINS];
    const int tid = threadIdx.x;
    const int tX = blockIdx.x, tY = blockIdx.y, ch = blockIdx.z;
    compute_G(kern, sG, tid);
    const float* inC = in + (size_t)ch * 256 * 256;
    const int N0y = 32 * tY - 9, N0x = 32 * tX - 9;
    load_patch(inC, sIn, tid, N0y, N0x, 0);
    __syncthreads();
    float tapA[17], tC6[6];
    read_taps(sG, tapA, tC6);
    horiz_pass(sIn, sMid, tapA, tC6, tid, 0);
    __syncthreads();
    const int c = tid & 31, gp = tid >> 5;
    float4 A[4][4];
#pragma unroll
    for (int i = 0; i < 4; ++i)
#pragma unroll
        for (int p = 0; p < 4; ++p) { A[i][p].x = 0.f; A[i][p].y = 0.f; A[i][p].z = 0.f; A[i][p].w = 0.f; }
#pragma unroll 1
    for (int l = 0; l < 16; ++l) {
        vert_pass(sMid, tapA, tC6, c, gp ^ (l & 7), A);
        __syncthreads();
    }
    float s = 0.f;
#pragma unroll
    for (int i = 0; i < 4; ++i)
#pragma unroll
        for (int p = 0; p < 4; ++p) s += A[i][p].x + A[i][p].y + A[i][p].z + A[i][p].w;
    asm volatile("" :: "v"(s));
}

extern "C" void kernel_launch(void* const* d_in, const int* in_sizes, int n_in,
                              void* d_out, int out_size, void* d_ws, size_t ws_size,
                              hipStream_t stream) {
    const float* x    = (const float*)d_in[0];   // (32, 256, 256)
    const float* kern = (const float*)d_in[1];   // 23 taps
    float* out  = (float*)d_out;                 // (32, 1024, 1024)

    dim3 grid(8, 8, 32);
    up4_fused<<<grid, dim3(256), 0, stream>>>(x, kern, out);
    abl_load <<<grid, dim3(256), 0, stream>>>(x);
    abl_horiz<<<grid, dim3(256), 0, stream>>>(x, kern);
    abl_vert <<<grid, dim3(256), 0, stream>>>(x, kern);
}

// Round 7
// 213.459 us; speedup vs baseline: 8.9472x; 8.9472x over previous
//
#include <hip/hip_runtime.h>

// Fused 4x upsample (two polyphase 2x stages composed): out[t] = sum_n g[t-2-4n] x[n],
// g = f (*) up2(f), 67 taps, circular, symmetric. Phases of out col/row t mod 4:
// 0 -> 12-tap (tC6), 1 -> 17-tap (tapA), 2 -> copy, 3 -> tapA reversed.
// Round-7: store-overlap restructure. r6 ablation: load ~2.2us, horiz ~4us, store drain
// ~21us (134MB) dominates; old kernel held A[4][4] to the end -> compute then store burst.
// Now: (1) copy-phase rows (out%4==2, 25% of output) stored straight from sMid right
// after the horiz barrier (stores start ~7us in); (2) vert pass split per-rowgroup
// (12 acc regs instead of 64), storing each rowgroup's 3 remaining phase-rows as soon
// as accumulated -> continuous store stream overlapping vert compute.

#define SINS 52      // sIn row stride (48 used + 4 pad; float4-aligned)
#define SMS 132      // sMid row stride (128 + 4 pad)

__device__ inline void fma4(float4& a, float t, const float4& r) {
    a.x += t * r.x; a.y += t * r.y; a.z += t * r.z; a.w += t * r.w;
}

__global__ __launch_bounds__(256, 4) void up4_fused(
    const float* __restrict__ in, const float* __restrict__ kern,
    float* __restrict__ out) {
    __shared__ float sG[80];
    __shared__ __attribute__((aligned(16))) float sMid[48][SMS];
    __shared__ __attribute__((aligned(16))) float sIn[48][SINS];

    const int tid = threadIdx.x;
    const int tX = blockIdx.x, tY = blockIdx.y, ch = blockIdx.z;

    // ---- compute g = f (*) up2(f) inline, threads 0..79: sG[u] = g[u-34] ----
    if (tid < 80) {
        const int s = tid - 34;
        int jlo = (s - 10) >> 1;        // ceil((s-11)/2)
        int jhi = (s + 11) >> 1;        // floor((s+11)/2)
        if (jlo < -11) jlo = -11;
        if (jhi > 11) jhi = 11;
        float acc = 0.f;
        for (int j = jlo; j <= jhi; ++j)
            acc += kern[11 + s - 2 * j] * kern[11 + j];
        sG[tid] = acc;
    }

    // ---- load 48x48 input patch (0-based): sIn[pi][pj] = inC[(N0y+1+pi)&255][(N0x+1+pj)&255]
    const float* inC = in + (size_t)ch * 256 * 256;
    const int N0y = 32 * tY - 9, N0x = 32 * tX - 9;
    const int gj0 = (N0x + 1) & 255;    // ≡ 0 (mod 8) -> float4-aligned
    if (gj0 <= 208) {
        // fast path: 48-col x-range contiguous (no wrap): 48 rows x 12 float4
#pragma unroll
        for (int it = 0; it < 3; ++it) {
            const int idx = tid + it * 256;         // 0..575
            if (idx < 576) {
                const int pi = idx / 12, m = idx % 12;
                const int gi = (N0y + 1 + pi + 256) & 255;
                *(float4*)&sIn[pi][4 * m] =
                    *(const float4*)&inC[gi * 256 + gj0 + 4 * m];
            }
        }
    } else {
        // wrap path (tX = 0 or 7): scalar with per-element wrap
#pragma unroll
        for (int it = 0; it < 9; ++it) {
            const int idx = tid + it * 256;         // 0..2303
            const int pi = idx / 48, pj = idx % 48;
            const int gi = (N0y + 1 + pi + 256) & 255;
            const int gj = (N0x + 1 + pj + 256) & 255;
            sIn[pi][pj] = inC[gi * 256 + gj];
        }
    }
    __syncthreads();

    // ---- taps in registers (g symmetric -> 23 regs), LDS broadcast reads ----
    float tapA[17], tC6[6];
#pragma unroll
    for (int k = 0; k < 17; ++k) tapA[k] = sG[1 + 4 * k];
#pragma unroll
    for (int m = 0; m < 6; ++m) tC6[m] = sG[12 + 4 * m];

    // ---- horizontal polyphase: 48 rows x 32 col-quads, 6 tasks/thread ----
    // 0-based window: quad c reads sIn[row][c .. c+16] via w = sIn[row][c+16-k]
#pragma unroll
    for (int it = 0; it < 6; ++it) {
        const int idx = tid + it * 256;             // 0..1535
        const int c = idx & 31, row = idx >> 5;
        float a0 = 0.f, a1 = 0.f, a2 = 0.f, a3 = 0.f;
#pragma unroll
        for (int k = 0; k < 17; ++k) {
            const float w = sIn[row][c + 16 - k];
            a1 += tapA[k] * w;
            a3 += tapA[16 - k] * w;
            if (k >= 3 && k <= 14) {
                const int m2 = k - 3;
                a0 += tC6[m2 < 6 ? m2 : 11 - m2] * w;
            }
            if (k == 8) a2 = w;
        }
        float4 v; v.x = a0; v.y = a1; v.z = a2; v.w = a3;
        *(float4*)&sMid[row][4 * c] = v;
    }
    __syncthreads();

    float* outC = out + (size_t)ch * 1024 * 1024;
    const int orow0 = 128 * tY, ocol0 = 128 * tX;

    // ---- copy-phase store: out local row 4r+2 = sMid[r+8], r = 0..31 ----
    // 25% of the output starts draining to HBM immediately after the horiz barrier.
#pragma unroll
    for (int it = 0; it < 4; ++it) {
        const int idx = tid + it * 256;             // 0..1023
        const int r = idx >> 5, cc = idx & 31;
        const float4 v = *(const float4*)&sMid[r + 8][4 * cc];
        *(float4*)&outC[(size_t)(orow0 + 4 * r + 2) * 1024 + ocol0 + 4 * cc] = v;
    }

    // ---- vertical polyphase: per-rowgroup split, store phases as completed ----
    // rowgroup R = 4*gp+i uses mid rows R..R+16: out local rows 4R+{0,1,3}
    const int c = tid & 31, gp = tid >> 5;          // c: col-quad, gp: 0..7
#pragma unroll
    for (int i = 0; i < 4; ++i) {
        const int R0 = 4 * gp + i;                  // base mid row of this rowgroup
        float4 a0, a1, a3;
        a0.x = a0.y = a0.z = a0.w = 0.f;
        a1.x = a1.y = a1.z = a1.w = 0.f;
        a3.x = a3.y = a3.z = a3.w = 0.f;
#pragma unroll
        for (int k = 0; k < 17; ++k) {
            const float4 R = *(const float4*)&sMid[R0 + 16 - k][4 * c];
            fma4(a1, tapA[k], R);
            fma4(a3, tapA[16 - k], R);
            if (k >= 3 && k <= 14) {
                const int m = k - 3;
                fma4(a0, tC6[m < 6 ? m : 11 - m], R);
            }
        }
        const size_t rbase = (size_t)(orow0 + 4 * R0) * 1024 + ocol0 + 4 * c;
        *(float4*)&outC[rbase]            = a0;     // phase 0
        *(float4*)&outC[rbase + 1024]     = a1;     // phase 1
        *(float4*)&outC[rbase + 3 * 1024] = a3;     // phase 3
    }
}

extern "C" void kernel_launch(void* const* d_in, const int* in_sizes, int n_in,
                              void* d_out, int out_size, void* d_ws, size_t ws_size,
                              hipStream_t stream) {
    const float* x    = (const float*)d_in[0];   // (32, 256, 256)
    const float* kern = (const float*)d_in[1];   // 23 taps
    float* out  = (float*)d_out;                 // (32, 1024, 1024)

    dim3 grid(8, 8, 32);                         // 128x128 output tiles
    up4_fused<<<grid, dim3(256), 0, stream>>>(x, kern, out);
}

// Round 8
// 150.391 us; speedup vs baseline: 12.6992x; 1.4194x over previous
//
#include <hip/hip_runtime.h>

// Fused 4x upsample (two polyphase 2x stages composed): out[t] = sum_n g[t-2-4n] x[n],
// g = f (*) up2(f), 67 taps, circular, symmetric. Phases of out col/row t mod 4:
// 0 -> 12-tap (tC6), 1 -> 17-tap (tapA), 2 -> copy, 3 -> tapA reversed.
// Round-8: r0 no-spill structure + minimal store-overlap. r7 showed the per-rowgroup
// split spilled (VGPR=64 cap, 460MB traffic, 106us). Here: (1) copy-phase rows
// (out%4==2 = sMid[8..39]) stored directly inside the horiz loop from the live v
// (zero extra reads, starts HBM drain ~4us in); (2) vert accumulator A[4][4]->A[4][3]
// (copy phase removed from the d-loop): 16 fewer VGPRs than r0. Vert d-loop identical.

#define SINS 52      // sIn row stride (48 used + 4 pad; float4-aligned)
#define SMS 132      // sMid row stride (128 + 4 pad)

__device__ inline void fma4(float4& a, float t, const float4& r) {
    a.x += t * r.x; a.y += t * r.y; a.z += t * r.z; a.w += t * r.w;
}

__global__ __launch_bounds__(256, 4) void up4_fused(
    const float* __restrict__ in, const float* __restrict__ kern,
    float* __restrict__ out) {
    __shared__ float sG[80];
    __shared__ __attribute__((aligned(16))) float sMid[48][SMS];
    __shared__ __attribute__((aligned(16))) float sIn[48][SINS];

    const int tid = threadIdx.x;
    const int tX = blockIdx.x, tY = blockIdx.y, ch = blockIdx.z;

    // ---- compute g = f (*) up2(f) inline, threads 0..79: sG[u] = g[u-34] ----
    if (tid < 80) {
        const int s = tid - 34;
        int jlo = (s - 10) >> 1;        // ceil((s-11)/2)
        int jhi = (s + 11) >> 1;        // floor((s+11)/2)
        if (jlo < -11) jlo = -11;
        if (jhi > 11) jhi = 11;
        float acc = 0.f;
        for (int j = jlo; j <= jhi; ++j)
            acc += kern[11 + s - 2 * j] * kern[11 + j];
        sG[tid] = acc;
    }

    // ---- load 48x48 input patch (0-based): sIn[pi][pj] = inC[(N0y+1+pi)&255][(N0x+1+pj)&255]
    const float* inC = in + (size_t)ch * 256 * 256;
    const int N0y = 32 * tY - 9, N0x = 32 * tX - 9;
    const int gj0 = (N0x + 1) & 255;    // ≡ 0 (mod 8) -> float4-aligned
    if (gj0 <= 208) {
        // fast path: 48-col x-range contiguous (no wrap): 48 rows x 12 float4
#pragma unroll
        for (int it = 0; it < 3; ++it) {
            const int idx = tid + it * 256;         // 0..575
            if (idx < 576) {
                const int pi = idx / 12, m = idx % 12;
                const int gi = (N0y + 1 + pi + 256) & 255;
                *(float4*)&sIn[pi][4 * m] =
                    *(const float4*)&inC[gi * 256 + gj0 + 4 * m];
            }
        }
    } else {
        // wrap path (tX = 0 or 7): scalar with per-element wrap
#pragma unroll
        for (int it = 0; it < 9; ++it) {
            const int idx = tid + it * 256;         // 0..2303
            const int pi = idx / 48, pj = idx % 48;
            const int gi = (N0y + 1 + pi + 256) & 255;
            const int gj = (N0x + 1 + pj + 256) & 255;
            sIn[pi][pj] = inC[gi * 256 + gj];
        }
    }
    __syncthreads();

    // ---- taps in registers (g symmetric -> 23 regs), LDS broadcast reads ----
    float tapA[17], tC6[6];
#pragma unroll
    for (int k = 0; k < 17; ++k) tapA[k] = sG[1 + 4 * k];
#pragma unroll
    for (int m = 0; m < 6; ++m) tC6[m] = sG[12 + 4 * m];

    float* outC = out + (size_t)ch * 1024 * 1024;
    const int orow0 = 128 * tY, ocol0 = 128 * tX;

    // ---- horizontal polyphase: 48 rows x 32 col-quads, 6 tasks/thread ----
    // 0-based window: quad c reads sIn[row][c .. c+16] via w = sIn[row][c+16-k].
    // Iterations 1..4 (sMid rows 8..39) double as copy-phase output rows 4*(row-8)+2:
    // store the live v straight to global (drain starts during horiz, no barrier wait).
#pragma unroll
    for (int it = 0; it < 6; ++it) {
        const int idx = tid + it * 256;             // 0..1535
        const int c = idx & 31, row = idx >> 5;
        float a0 = 0.f, a1 = 0.f, a2 = 0.f, a3 = 0.f;
#pragma unroll
        for (int k = 0; k < 17; ++k) {
            const float w = sIn[row][c + 16 - k];
            a1 += tapA[k] * w;
            a3 += tapA[16 - k] * w;
            if (k >= 3 && k <= 14) {
                const int m2 = k - 3;
                a0 += tC6[m2 < 6 ? m2 : 11 - m2] * w;
            }
            if (k == 8) a2 = w;
        }
        float4 v; v.x = a0; v.y = a1; v.z = a2; v.w = a3;
        *(float4*)&sMid[row][4 * c] = v;
        if (it >= 1 && it <= 4)                     // compile-time per iteration
            *(float4*)&outC[(size_t)(orow0 + 4 * (row - 8) + 2) * 1024 + ocol0 + 4 * c] = v;
    }
    __syncthreads();

    // ---- vertical polyphase: 4 row-groups/thread, rolling 20-row window ----
    // A[i][0]=phase0 (tC6), A[i][1]=phase1 (tapA), A[i][2]=phase3 (tapA reversed).
    const int c = tid & 31, gp = tid >> 5;          // c: col-quad, gp: 0..7
    float4 A[4][3];
#pragma unroll
    for (int i = 0; i < 4; ++i)
#pragma unroll
        for (int p = 0; p < 3; ++p) { A[i][p].x = 0.f; A[i][p].y = 0.f; A[i][p].z = 0.f; A[i][p].w = 0.f; }

#pragma unroll
    for (int d = 1; d <= 20; ++d) {
        const float4 R = *(const float4*)&sMid[4 * gp + d - 1][4 * c];
#pragma unroll
        for (int i = 0; i < 4; ++i) {
            const int k = i + 17 - d;               // tap index for row-group 4*gp+i
            if (k < 0 || k > 16) continue;
            fma4(A[i][1], tapA[k], R);
            fma4(A[i][2], tapA[16 - k], R);
            if (k >= 3 && k <= 14) {
                const int m = k - 3;
                fma4(A[i][0], tC6[m < 6 ? m : 11 - m], R);
            }
        }
    }

#pragma unroll
    for (int i = 0; i < 4; ++i) {
        const int R0 = 4 * gp + i;                  // rowgroup: out local rows 4*R0+{0,1,3}
        const size_t rbase = (size_t)(orow0 + 4 * R0) * 1024 + ocol0 + 4 * c;
        *(float4*)&outC[rbase]            = A[i][0];    // phase 0
        *(float4*)&outC[rbase + 1024]     = A[i][1];    // phase 1
        *(float4*)&outC[rbase + 3 * 1024] = A[i][2];    // phase 3
    }
}

extern "C" void kernel_launch(void* const* d_in, const int* in_sizes, int n_in,
                              void* d_out, int out_size, void* d_ws, size_t ws_size,
                              hipStream_t stream) {
    const float* x    = (const float*)d_in[0];   // (32, 256, 256)
    const float* kern = (const float*)d_in[1];   // 23 taps
    float* out  = (float*)d_out;                 // (32, 1024, 1024)

    dim3 grid(8, 8, 32);                         // 128x128 output tiles
    up4_fused<<<grid, dim3(256), 0, stream>>>(x, kern, out);
}